// Round 10
// baseline (175.496 us; speedup 1.0000x reference)
//
#include <hip/hip_runtime.h>
#include <hip/hip_cooperative_groups.h>
#include <cfloat>

// Problem constants (from reference): B=8, C=2, H=256, W=256
#define BB 8
#define CC 2
#define HH 256
#define WW 256

typedef unsigned long long ull;
namespace cg = cooperative_groups;

static constexpr float EDT_INF = 1e4f;          // matches reference INF
static constexpr int   NPIX    = BB * HH * WW;  // 524288
#define NBLK 512                                // cooperative grid size

// ---------------------------------------------------------------------------
// Distance^2 to nearest SET bit of zm (the zeros of the selected field),
// reproducing the reference f32 scan exactly (sentinels 1e4+pos+1 /
// 1e4+256-pos, g = fminf(fwd,bwd), return g*g).
__device__ __forceinline__ float hdist2(const ull* zm, int pos) {
    float fwd = EDT_INF + (float)(pos + 1);
    {
        int k = pos - 1;
        if (k >= 0) {
            int w = k >> 6;
            ull t = zm[w] & (~0ULL >> (63 - (k & 63)));
            for (;;) {
                if (t) { int j = (w << 6) + 63 - __builtin_clzll(t); fwd = (float)(pos - j); break; }
                if (--w < 0) break;
                t = zm[w];
            }
        }
    }
    float bwd = EDT_INF + (float)(256 - pos);
    {
        int k = pos + 1;
        if (k < 256) {
            int w = k >> 6;
            ull t = zm[w] & (~0ULL << (k & 63));
            for (;;) {
                if (t) { int j = (w << 6) + __builtin_ctzll(t); bwd = (float)(j - pos); break; }
                if (++w >= 4) break;
                t = zm[w];
            }
        }
    }
    float g = fminf(fwd, bwd);
    return g * g;
}

// Nearest SET bit distance (int), large sentinel when none.
__device__ __forceinline__ int nearest_set(const ull* zm, int pos) {
    int best = 1 << 20;
    {
        int k = pos - 1;
        if (k >= 0) {
            int w = k >> 6;
            ull t = zm[w] & (~0ULL >> (63 - (k & 63)));
            for (;;) {
                if (t) { int j = (w << 6) + 63 - __builtin_clzll(t); best = pos - j; break; }
                if (--w < 0) break;
                t = zm[w];
            }
        }
    }
    {
        int k = pos + 1;
        if (k < 256) {
            int w = k >> 6;
            ull t = zm[w] & (~0ULL << (k & 63));
            for (;;) {
                if (t) { int j = (w << 6) + __builtin_ctzll(t); best = min(best, j - pos); break; }
                if (++w >= 4) break;
                t = zm[w];
            }
        }
    }
    return best;
}

// ---------------------------------------------------------------------------
// Shared device code: per-column fused EDT + final math -> partial sum for
// column (b,j). i = threadIdx.x = row. Uses caller-provided LDS buffers.
__device__ __forceinline__ float column_partial(
        const int* __restrict__ target, int b, int j, int i, int tmin,
        const ull wp[4], const ull wg[4],
        float* s_p, float* s_g, ull* cshP, ull* cshG, float* sws) {
    const int wv = i >> 6, ln = i & 63;
    const bool pc = (wp[j >> 6] >> (j & 63)) & 1ULL;
    const bool gt = (wg[j >> 6] >> (j & 63)) & 1ULL;

    // own-polarity zero-masks
    ull zp[4], zg[4];
#pragma unroll
    for (int k = 0; k < 4; ++k) {
        zp[k] = pc ? ~wp[k] : wp[k];
        zg[k] = gt ? ~wg[k] : wg[k];
    }
    s_p[i] = hdist2(zp, j);
    s_g[i] = hdist2(zg, j);
    {
        ull bp = __ballot(pc);
        ull bg = __ballot(gt);
        if (ln == 0) { cshP[wv] = bp; cshG[wv] = bg; }
    }
    __syncthreads();

    // column opposite-polarity masks
    ull cp[4], cgm[4];
#pragma unroll
    for (int k = 0; k < 4; ++k) {
        ull P = cshP[k], G = cshG[k];
        cp[k]  = pc ? ~P : P;
        cgm[k] = gt ? ~G : G;
    }
    const int dvp = nearest_set(cp, i);
    const int dvg = nearest_set(cgm, i);

    // pc vertical search, pruned
    float mn = s_p[i];
    {
        int dmax = min(dvp, HH);
        for (int d = 1; d < dmax; ++d) {
            float dd = (float)(d * d);
            if (dd >= mn) break;
            int kl = i - d, kr = i + d;
            if (kl >= 0) mn = fminf(mn, dd + s_p[kl]);
            if (kr < HH) mn = fminf(mn, dd + s_p[kr]);
        }
        float dv = (float)dvp;
        mn = fminf(mn, dv * dv);
    }
    float pd = sqrtf(mn);

    // gt vertical search, pruned
    float mg = s_g[i];
    {
        int dmax = min(dvg, HH);
        for (int d = 1; d < dmax; ++d) {
            float dd = (float)(d * d);
            if (dd >= mg) break;
            int kl = i - d, kr = i + d;
            if (kl >= 0) mg = fminf(mg, dd + s_g[kl]);
            if (kr < HH) mg = fminf(mg, dd + s_g[kr]);
        }
        float dv = (float)dvg;
        mg = fminf(mg, dv * dv);
    }
    float gd = sqrtf(mg);

    // final elementwise math (reference op order)
    int tv = target[((size_t)b * HH + i) * WW + j];
    if (tv == 255) tv = tmin;
    float gtv = (float)tv;
    float pcv = pc ? 1.0f : 0.0f;
    float err  = fabsf(gtv - pcv);
    float dist = sqrtf(pd * pd + gd * gd);
    float mult = sqrtf(err * dist + 1e-9f);

    // deterministic block sum: wave shfl-add + fixed-order 4-term merge
    for (int off = 32; off > 0; off >>= 1) mult += __shfl_down(mult, off);
    if (ln == 0) sws[wv] = mult;
    __syncthreads();
    return ((sws[0] + sws[1]) + sws[2]) + sws[3];
}

// ---------------------------------------------------------------------------
// Single cooperative kernel, 512 blocks x 256 threads (low co-residency
// requirement: 2 blocks/CU; R9 lesson — 1024 blocks was likely rejected by
// the cooperative occupancy check at ~150 VGPR).
__global__ void __launch_bounds__(256, 2)
k_all(const float* __restrict__ preds, const int* __restrict__ target,
      ull* __restrict__ mPC, ull* __restrict__ mGT0, ull* __restrict__ mG255,
      int* __restrict__ tminPart, float* __restrict__ partials,
      float* __restrict__ out) {
    cg::grid_group grid = cg::this_grid();
    const int blk = blockIdx.x;
    const int tid = threadIdx.x;
    const int wv = tid >> 6, ln = tid & 63;

    __shared__ float s_p[HH], s_g[HH];
    __shared__ ull   cshP[4], cshG[4];
    __shared__ int   sti[4];
    __shared__ float sws[4];

    // ---------------- Phase A: masks for rows 4*blk .. 4*blk+3 --------------
    {
        int tl = 0x7fffffff;
#pragma unroll
        for (int rr = 0; rr < 4; ++rr) {
            int r = blk * 4 + rr;
            int b = r >> 8, i = r & 255;
            float a0 = preds[((size_t)b * CC + 0) * HH * WW + (size_t)i * WW + tid];
            float a1 = preds[((size_t)b * CC + 1) * HH * WW + (size_t)i * WW + tid];
            bool pc = (a1 > a0);           // argmax over C=2, ties -> class 0
            int tv = target[((size_t)b * HH + i) * WW + tid];
            tl = min(tl, tv);
            ull bp = __ballot(pc);
            ull b0 = __ballot(tv > 0);
            ull b2 = __ballot(tv == 255);
            if (ln == 0) {
                size_t midx = ((size_t)b * HH + i) * 4 + wv;
                mPC[midx] = bp; mGT0[midx] = b0; mG255[midx] = b2;
            }
        }
        for (int off = 32; off > 0; off >>= 1) tl = min(tl, __shfl_down(tl, off));
        if (ln == 0) sti[wv] = tl;
        __syncthreads();
        if (tid == 0)
            tminPart[blk] = min(min(sti[0], sti[1]), min(sti[2], sti[3]));
    }

    __threadfence();
    grid.sync();

    // ---------------- Phase B: 4 columns of image blk>>6 --------------------
    const int b  = blk >> 6;
    const int jg = blk & 63;
    const int i  = tid;                    // row

    // tmin = min over NBLK partials
    int tmin;
    {
        int v = min(tminPart[tid], tminPart[tid + 256]);
        for (int off = 32; off > 0; off >>= 1) v = min(v, __shfl_down(v, off));
        __syncthreads();                   // sti reuse
        if (ln == 0) sti[wv] = v;
        __syncthreads();
        tmin = min(min(sti[0], sti[1]), min(sti[2], sti[3]));
    }
    const bool allpos = (tmin > 0);

    // row i's masks (image b): loaded once, serve all 4 columns
    ull wp[4], wg[4];
    {
        const ull* pP = mPC   + ((size_t)b * HH + i) * 4;
        const ull* p0 = mGT0  + ((size_t)b * HH + i) * 4;
        const ull* p2 = mG255 + ((size_t)b * HH + i) * 4;
#pragma unroll
        for (int k = 0; k < 4; ++k) {
            wp[k] = pP[k];
            ull g = p0[k];
            if (!allpos) g &= ~p2[k];      // 255 -> tmin==0 -> not >0
            wg[k] = g;
        }
    }

    for (int c = 0; c < 4; ++c) {
        const int j = jg * 4 + c;
        float psum = column_partial(target, b, j, i, tmin, wp, wg,
                                    s_p, s_g, cshP, cshG, sws);
        if (tid == 0) partials[blk * 4 + c] = psum;   // = b*256 + j
        __syncthreads();                   // protect LDS for next c
    }

    __threadfence();
    grid.sync();

    // ---------------- Phase C: block 0 reduces 2048 partials ----------------
    if (blk == 0) {
        __shared__ float s[256];
        float acc = 0.0f;
        for (int k = tid; k < BB * WW; k += 256) acc += partials[k];
        s[tid] = acc;
        __syncthreads();
        for (int st = 128; st > 0; st >>= 1) {
            if (tid < st) s[tid] += s[tid + st];
            __syncthreads();
        }
        if (tid == 0) out[0] = s[0] * (1.0f / (float)NPIX);  // /2^19: exact
    }
}

// ---------------------------------------------------------------------------
// Fallback path (R8-proven, 25 us): 3 plain kernels.
__global__ void k_masks(const float* __restrict__ preds,
                        const int*   __restrict__ target,
                        ull* __restrict__ mPC, ull* __restrict__ mGT0,
                        ull* __restrict__ mG255, int* __restrict__ tminPart) {
    const int blk = blockIdx.x;
    const int b  = blk >> 5;
    const int ig = blk & 31;
    const int wv = threadIdx.x >> 6;
    const int ln = threadIdx.x & 63;
    const int w  = (wv << 6) | ln;

    int tmin = 0x7fffffff;
#pragma unroll
    for (int r = 0; r < 8; ++r) {
        int i = ig * 8 + r;
        float a0 = preds[((size_t)b * CC + 0) * HH * WW + (size_t)i * WW + w];
        float a1 = preds[((size_t)b * CC + 1) * HH * WW + (size_t)i * WW + w];
        bool pc = (a1 > a0);
        int tv = target[((size_t)b * HH + i) * WW + w];
        tmin = min(tmin, tv);
        ull bp = __ballot(pc);
        ull b0 = __ballot(tv > 0);
        ull b2 = __ballot(tv == 255);
        if (ln == 0) {
            size_t midx = ((size_t)b * HH + i) * 4 + wv;
            mPC[midx] = bp; mGT0[midx] = b0; mG255[midx] = b2;
        }
    }
    for (int off = 32; off > 0; off >>= 1) tmin = min(tmin, __shfl_down(tmin, off));
    __shared__ int swv[4];
    if (ln == 0) swv[wv] = tmin;
    __syncthreads();
    if (threadIdx.x == 0)
        tminPart[blk] = min(min(swv[0], swv[1]), min(swv[2], swv[3]));
}

__global__ void k_fused(const int* __restrict__ target,
                        const ull* __restrict__ mPC,
                        const ull* __restrict__ mGT0,
                        const ull* __restrict__ mG255,
                        const int* __restrict__ tminPart,
                        float* __restrict__ partials) {
    const int blk = blockIdx.x;            // b*256 + j
    const int b = blk >> 8, j = blk & 255;
    const int i = threadIdx.x;
    const int wv = i >> 6, ln = i & 63;

    __shared__ float s_p[HH], s_g[HH];
    __shared__ ull   cshP[4], cshG[4];
    __shared__ int   stw[4];
    __shared__ float sws[4];

    {
        int v = tminPart[i];
        for (int off = 32; off > 0; off >>= 1) v = min(v, __shfl_down(v, off));
        if (ln == 0) stw[wv] = v;
    }
    __syncthreads();
    const int tmin = min(min(stw[0], stw[1]), min(stw[2], stw[3]));
    const bool allpos = (tmin > 0);

    ull wp[4], wg[4];
    {
        const ull* pP = mPC   + ((size_t)b * HH + i) * 4;
        const ull* p0 = mGT0  + ((size_t)b * HH + i) * 4;
        const ull* p2 = mG255 + ((size_t)b * HH + i) * 4;
#pragma unroll
        for (int k = 0; k < 4; ++k) {
            wp[k] = pP[k];
            ull g = p0[k];
            if (!allpos) g &= ~p2[k];
            wg[k] = g;
        }
    }

    float psum = column_partial(target, b, j, i, tmin, wp, wg,
                                s_p, s_g, cshP, cshG, sws);
    if (i == 0) partials[blk] = psum;
}

__global__ void k_final(const float* __restrict__ partials, float* __restrict__ out) {
    __shared__ float s[256];
    float acc = 0.0f;
    for (int k = threadIdx.x; k < BB * WW; k += 256) acc += partials[k];
    s[threadIdx.x] = acc;
    __syncthreads();
    for (int st = 128; st > 0; st >>= 1) {
        if (threadIdx.x < st) s[threadIdx.x] += s[threadIdx.x + st];
        __syncthreads();
    }
    if (threadIdx.x == 0) out[0] = s[0] * (1.0f / (float)NPIX);
}

// ---------------------------------------------------------------------------
extern "C" void kernel_launch(void* const* d_in, const int* in_sizes, int n_in,
                              void* d_out, int out_size, void* d_ws, size_t ws_size,
                              hipStream_t stream) {
    const float* preds  = (const float*)d_in[0];
    const int*   target = (const int*)d_in[1];
    float* out = (float*)d_out;

    // ws layout: 3 mask arrays, tmin partials (512), column partials (2048)
    ull* mPC   = (ull*)d_ws;                         // 8*256*4 ULL
    ull* mGT0  = mPC  + (size_t)BB * HH * 4;
    ull* mG255 = mGT0 + (size_t)BB * HH * 4;
    int*   tminPart = (int*)(mG255 + (size_t)BB * HH * 4);     // NBLK ints
    float* partials = (float*)(tminPart + NBLK);               // B*W floats

    void* args[] = {(void*)&preds, (void*)&target, (void*)&mPC, (void*)&mGT0,
                    (void*)&mG255, (void*)&tminPart, (void*)&partials,
                    (void*)&out};
    hipError_t e = hipLaunchCooperativeKernel((void*)k_all, dim3(NBLK),
                                              dim3(256), args, 0, stream);
    if (e != hipSuccess) {
        // R8-proven 3-kernel fallback (deterministic: same env -> same path)
        (void)hipGetLastError();           // clear error state
        k_masks<<<256, 256, 0, stream>>>(preds, target, mPC, mGT0, mG255, tminPart);
        k_fused<<<BB * WW, HH, 0, stream>>>(target, mPC, mGT0, mG255, tminPart, partials);
        k_final<<<1, 256, 0, stream>>>(partials, out);
    }
}

// Round 11
// 33.205 us; speedup vs baseline: 5.2852x; 5.2852x over previous
//
#include <hip/hip_runtime.h>
#include <cfloat>

// Problem constants (from reference): B=8, C=2, H=256, W=256
#define BB 8
#define CC 2
#define HH 256
#define WW 256

typedef unsigned long long ull;

static constexpr float EDT_INF = 1e4f;          // matches reference INF
static constexpr int   NPIX    = BB * HH * WW;  // 524288
#define FBLK 512                                // k_fused grid (4 cols/block)

// ---------------------------------------------------------------------------
// Distance^2 to nearest SET bit of zm (the zeros of the selected field),
// reproducing the reference f32 scan exactly (sentinels 1e4+pos+1 /
// 1e4+256-pos, g = fminf(fwd,bwd), return g*g).
__device__ __forceinline__ float hdist2(const ull* zm, int pos) {
    float fwd = EDT_INF + (float)(pos + 1);
    {
        int k = pos - 1;
        if (k >= 0) {
            int w = k >> 6;
            ull t = zm[w] & (~0ULL >> (63 - (k & 63)));
            for (;;) {
                if (t) { int j = (w << 6) + 63 - __builtin_clzll(t); fwd = (float)(pos - j); break; }
                if (--w < 0) break;
                t = zm[w];
            }
        }
    }
    float bwd = EDT_INF + (float)(256 - pos);
    {
        int k = pos + 1;
        if (k < 256) {
            int w = k >> 6;
            ull t = zm[w] & (~0ULL << (k & 63));
            for (;;) {
                if (t) { int j = (w << 6) + __builtin_ctzll(t); bwd = (float)(j - pos); break; }
                if (++w >= 4) break;
                t = zm[w];
            }
        }
    }
    float g = fminf(fwd, bwd);
    return g * g;
}

// Nearest SET bit distance (int), large sentinel when none.
__device__ __forceinline__ int nearest_set(const ull* zm, int pos) {
    int best = 1 << 20;
    {
        int k = pos - 1;
        if (k >= 0) {
            int w = k >> 6;
            ull t = zm[w] & (~0ULL >> (63 - (k & 63)));
            for (;;) {
                if (t) { int j = (w << 6) + 63 - __builtin_clzll(t); best = pos - j; break; }
                if (--w < 0) break;
                t = zm[w];
            }
        }
    }
    {
        int k = pos + 1;
        if (k < 256) {
            int w = k >> 6;
            ull t = zm[w] & (~0ULL << (k & 63));
            for (;;) {
                if (t) { int j = (w << 6) + __builtin_ctzll(t); best = min(best, j - pos); break; }
                if (++w >= 4) break;
                t = zm[w];
            }
        }
    }
    return best;
}

// ---------------------------------------------------------------------------
// K1: build ROW masks (coalesced: lanes across w) + per-block tmin partials.
// Block 0 also resets the completion counter for K2 (runs first in stream
// order each call; ws is not re-poisoned between replays).
__global__ void k_masks(const float* __restrict__ preds,
                        const int*   __restrict__ target,
                        ull* __restrict__ mPC, ull* __restrict__ mGT0,
                        ull* __restrict__ mG255, int* __restrict__ tminPart,
                        unsigned int* __restrict__ count) {
    const int blk = blockIdx.x;
    const int b  = blk >> 5;               // image
    const int ig = blk & 31;               // 8-row group
    const int wv = threadIdx.x >> 6;       // word index 0..3
    const int ln = threadIdx.x & 63;
    const int w  = (wv << 6) | ln;

    if (blk == 0 && threadIdx.x == 0) *count = 0u;

    int tmin = 0x7fffffff;
#pragma unroll
    for (int r = 0; r < 8; ++r) {
        int i = ig * 8 + r;
        float a0 = preds[((size_t)b * CC + 0) * HH * WW + (size_t)i * WW + w];
        float a1 = preds[((size_t)b * CC + 1) * HH * WW + (size_t)i * WW + w];
        bool pc = (a1 > a0);               // argmax over C=2, ties -> class 0
        int tv = target[((size_t)b * HH + i) * WW + w];
        tmin = min(tmin, tv);
        ull bp = __ballot(pc);
        ull b0 = __ballot(tv > 0);
        ull b2 = __ballot(tv == 255);
        if (ln == 0) {
            size_t midx = ((size_t)b * HH + i) * 4 + wv;
            mPC[midx] = bp; mGT0[midx] = b0; mG255[midx] = b2;
        }
    }
    for (int off = 32; off > 0; off >>= 1) tmin = min(tmin, __shfl_down(tmin, off));
    __shared__ int swv[4];
    if (ln == 0) swv[wv] = tmin;
    __syncthreads();
    if (threadIdx.x == 0)
        tminPart[blk] = min(min(swv[0], swv[1]), min(swv[2], swv[3]));
}

// ---------------------------------------------------------------------------
// Per-column fused EDT + final math -> block-wide partial sum for column
// (b,j). i = threadIdx.x = row. Uses caller-provided LDS buffers.
__device__ __forceinline__ float column_partial(
        const int* __restrict__ target, int b, int j, int i, int tmin,
        const ull wp[4], const ull wg[4],
        float* s_p, float* s_g, ull* cshP, ull* cshG, float* sws) {
    const int wv = i >> 6, ln = i & 63;
    const bool pc = (wp[j >> 6] >> (j & 63)) & 1ULL;
    const bool gt = (wg[j >> 6] >> (j & 63)) & 1ULL;

    // own-polarity zero-masks
    ull zp[4], zg[4];
#pragma unroll
    for (int k = 0; k < 4; ++k) {
        zp[k] = pc ? ~wp[k] : wp[k];
        zg[k] = gt ? ~wg[k] : wg[k];
    }
    s_p[i] = hdist2(zp, j);
    s_g[i] = hdist2(zg, j);
    {
        ull bp = __ballot(pc);
        ull bg = __ballot(gt);
        if (ln == 0) { cshP[wv] = bp; cshG[wv] = bg; }
    }
    __syncthreads();

    // column opposite-polarity masks
    ull cp[4], cgm[4];
#pragma unroll
    for (int k = 0; k < 4; ++k) {
        ull P = cshP[k], G = cshG[k];
        cp[k]  = pc ? ~P : P;
        cgm[k] = gt ? ~G : G;
    }
    const int dvp = nearest_set(cp, i);
    const int dvg = nearest_set(cgm, i);

    // pc vertical search, pruned (opposite rows give exactly d^2 candidates)
    float mn = s_p[i];
    {
        int dmax = min(dvp, HH);
        for (int d = 1; d < dmax; ++d) {
            float dd = (float)(d * d);
            if (dd >= mn) break;
            int kl = i - d, kr = i + d;
            if (kl >= 0) mn = fminf(mn, dd + s_p[kl]);
            if (kr < HH) mn = fminf(mn, dd + s_p[kr]);
        }
        float dv = (float)dvp;
        mn = fminf(mn, dv * dv);
    }
    float pd = sqrtf(mn);

    // gt vertical search, pruned
    float mg = s_g[i];
    {
        int dmax = min(dvg, HH);
        for (int d = 1; d < dmax; ++d) {
            float dd = (float)(d * d);
            if (dd >= mg) break;
            int kl = i - d, kr = i + d;
            if (kl >= 0) mg = fminf(mg, dd + s_g[kl]);
            if (kr < HH) mg = fminf(mg, dd + s_g[kr]);
        }
        float dv = (float)dvg;
        mg = fminf(mg, dv * dv);
    }
    float gd = sqrtf(mg);

    // final elementwise math (reference op order)
    int tv = target[((size_t)b * HH + i) * WW + j];
    if (tv == 255) tv = tmin;
    float gtv = (float)tv;
    float pcv = pc ? 1.0f : 0.0f;
    float err  = fabsf(gtv - pcv);
    float dist = sqrtf(pd * pd + gd * gd);
    float mult = sqrtf(err * dist + 1e-9f);

    // deterministic block sum: wave shfl-add + fixed-order 4-term merge
    for (int off = 32; off > 0; off >>= 1) mult += __shfl_down(mult, off);
    if (ln == 0) sws[wv] = mult;
    __syncthreads();
    return ((sws[0] + sws[1]) + sws[2]) + sws[3];
}

// ---------------------------------------------------------------------------
// K2: 512 blocks x 256 threads; block = (image b, column group jg) handles
// columns jg*4..jg*4+3 (masks loaded once per block). Writes its partial,
// then ONE atomicAdd(count); the last-arriving block (staggered finish ->
// no pile-up, R4 lesson) does the fixed-order final reduction.
__global__ void __launch_bounds__(256)
k_fused(const int* __restrict__ target,
        const ull* __restrict__ mPC,
        const ull* __restrict__ mGT0,
        const ull* __restrict__ mG255,
        const int* __restrict__ tminPart,
        float* __restrict__ partialB,
        unsigned int* __restrict__ count,
        float* __restrict__ out) {
    const int blk = blockIdx.x;            // b*64 + jg
    const int b = blk >> 6, jg = blk & 63;
    const int i = threadIdx.x;             // row
    const int wv = i >> 6, ln = i & 63;

    __shared__ float s_p[HH], s_g[HH];
    __shared__ ull   cshP[4], cshG[4];
    __shared__ int   stw[4];
    __shared__ float sws[4];
    __shared__ float sred[256];
    __shared__ int   lastFlag;

    // tmin = min of the 256 k_masks partials
    {
        int v = tminPart[i];
        for (int off = 32; off > 0; off >>= 1) v = min(v, __shfl_down(v, off));
        if (ln == 0) stw[wv] = v;
    }
    __syncthreads();
    const int tmin = min(min(stw[0], stw[1]), min(stw[2], stw[3]));
    const bool allpos = (tmin > 0);

    // row i's masks (image b): loaded once, serve all 4 columns
    ull wp[4], wg[4];
    {
        const ull* pP = mPC   + ((size_t)b * HH + i) * 4;
        const ull* p0 = mGT0  + ((size_t)b * HH + i) * 4;
        const ull* p2 = mG255 + ((size_t)b * HH + i) * 4;
#pragma unroll
        for (int k = 0; k < 4; ++k) {
            wp[k] = pP[k];
            ull g = p0[k];
            if (!allpos) g &= ~p2[k];      // 255 -> tmin==0 -> not >0
            wg[k] = g;
        }
    }

    float bsum = 0.0f;                     // fixed-order 4-column accumulation
    for (int c = 0; c < 4; ++c) {
        const int j = jg * 4 + c;
        float psum = column_partial(target, b, j, i, tmin, wp, wg,
                                    s_p, s_g, cshP, cshG, sws);
        bsum += psum;
        __syncthreads();                   // protect LDS for next column
    }

    if (i == 0) {
        partialB[blk] = bsum;
        __threadfence();                   // publish before the count bump
        unsigned int old = atomicAdd(count, 1u);
        lastFlag = (old == (unsigned int)(FBLK - 1)) ? 1 : 0;
    }
    __syncthreads();

    if (lastFlag) {
        __threadfence();                   // acquire: see all partialB writes
        float acc = partialB[i] + partialB[i + 256];
        sred[i] = acc;
        __syncthreads();
        for (int st = 128; st > 0; st >>= 1) {
            if (i < st) sred[i] += sred[i + st];
            __syncthreads();
        }
        if (i == 0) out[0] = sred[0] * (1.0f / (float)NPIX);  // /2^19: exact
    }
}

// ---------------------------------------------------------------------------
extern "C" void kernel_launch(void* const* d_in, const int* in_sizes, int n_in,
                              void* d_out, int out_size, void* d_ws, size_t ws_size,
                              hipStream_t stream) {
    const float* preds  = (const float*)d_in[0];
    const int*   target = (const int*)d_in[1];
    float* out = (float*)d_out;

    // ws layout: 3 mask arrays, tmin partials (256), block partials (512), count
    ull* mPC   = (ull*)d_ws;                         // 8*256*4 ULL
    ull* mGT0  = mPC  + (size_t)BB * HH * 4;
    ull* mG255 = mGT0 + (size_t)BB * HH * 4;
    int*   tminPart = (int*)(mG255 + (size_t)BB * HH * 4);     // 256 ints
    float* partialB = (float*)(tminPart + 256);                // FBLK floats
    unsigned int* count = (unsigned int*)(partialB + FBLK);    // 1 uint

    k_masks<<<256, 256, 0, stream>>>(preds, target, mPC, mGT0, mG255,
                                     tminPart, count);
    k_fused<<<FBLK, 256, 0, stream>>>(target, mPC, mGT0, mG255, tminPart,
                                      partialB, count, out);
}